// Round 12
// baseline (291.867 us; speedup 1.0000x reference)
//
#include <hip/hip_runtime.h>
#include <hip/hip_bf16.h>

// QKVAttention: L2-distance attention. B=8, T=4096, C=192, fp32 in/out.
// out[b,t,:] = sum_s exp(-||q_t-k_s||*192^-0.5) v_s / sum_s exp(...)
// exp arg bounded in [-3,0] -> no online softmax needed.
//
// R16 = R14 core with V MOVED OUT OF LDS (global->register PV operands).
// Post-mortems R10-R15 falsified: occupancy, barriers, setprio, per-score
// VALU, MFMA chain depth. Corrected pipe audit: DS pipe (per-CU, 8 waves)
// serves 26 b128 reads + 8 w + 6KB staging ~= 430 cyc/wave-iter = 95-115%
// of the 157us budget -> DS is the only pipe at ceiling. V needs no layout
// transform and is L1-resident (12KB/iter/blk, 4-wave reuse) -> load vf[]
// straight from vsw with global_load_dwordx4 issued BEFORE stage() (vmcnt
// wait before PV then leaves K-staging in flight). DS/wave-iter -42%.
//  - vsw relayout ((b*128+sc)*12+nt) -> one pointer += 12288/iter, nt*1024
//    immediate offsets.
//  - LDS 33792B = K dbuf 24KB + P scratch 9KB (V region deleted).
//  - prep/P-path/epilogue/numerics identical to R14 (V bits unchanged).

#define BB 8
#define TT 4096
#define CD 192

typedef __attribute__((ext_vector_type(8))) short short8;   // 8 bf16 (4 VGPR)
typedef __attribute__((ext_vector_type(4))) float float4v;  // MFMA C/D
typedef __attribute__((ext_vector_type(4))) unsigned uint4v;
typedef __attribute__((ext_vector_type(2))) unsigned int uint2v;

// (log2 e)^2 / 192  : p = exp2(-sqrt(max(q2A+k2A-2*A2C*dot, 0)))
constexpr float A2C = (float)(2.0813689810056077 / 192.0);

static __device__ __forceinline__ unsigned short f2bf(float f) {
  unsigned u = __builtin_bit_cast(unsigned, f);
  unsigned r = u + 0x7fffu + ((u >> 16) & 1u);   // RNE (inputs finite)
  return (unsigned short)(r >> 16);
}
static __device__ __forceinline__ float bf2f(unsigned short b) {
  return __builtin_bit_cast(float, (unsigned)b << 16);
}
static __device__ __forceinline__ unsigned cvtpk_bf16(float lo, float hi) {
  unsigned r;                  // D[15:0]=bf16(lo), D[31:16]=bf16(hi), RNE
  asm("v_cvt_pk_bf16_f32 %0, %1, %2" : "=v"(r) : "v"(lo), "v"(hi));
  return r;
}

// ---------------- fused prepass: qkv -> qsw/ksw/vsw fragments + q2/k2 -------
// block = (b, sc): 32 tokens x 576 ch. Coalesced float4 read -> bf16 LDS tile,
// then emit MFMA-fragment units (64 lanes x 16B each) + A2C-prescaled rounded
// row sumsq. No atomics: each block owns its 32 tokens' q2/k2 entries.
__global__ __launch_bounds__(256) void prep(
    const float* __restrict__ qkv, short8* __restrict__ qsw,
    short8* __restrict__ ksw, short8* __restrict__ vsw,
    float* __restrict__ q2, float* __restrict__ k2) {
  __shared__ unsigned short tile[32 * 584];   // row stride 584 (1168B, 16-mult)
  const int t = threadIdx.x;
  const int b = blockIdx.x >> 7;
  const int sc = blockIdx.x & 127;
  const float* src = qkv + ((size_t)(b * TT + sc * 32)) * (3 * CD);
#pragma unroll
  for (int j = 0; j < 18; ++j) {              // 4608 float4s / 256 thr
    int f = j * 256 + t;
    int row = f / 144, c4 = (f % 144) * 4;
    float4v x = *(const float4v*)(src + (size_t)row * 576 + c4);
    unsigned r0 = cvtpk_bf16(x[0], x[1]);     // HW RNE pack
    unsigned r1 = cvtpk_bf16(x[2], x[3]);
    *(uint2v*)&tile[row * 584 + c4] = (uint2v){r0, r1};
  }
  __syncthreads();

  const int lane = t & 63, w = t >> 6;
  const int L = lane & 15, q = lane >> 4;
  // waves 0,1 -> q (s16o = w), waves 2,3 -> k (s16o = w-2)
  const int which = w >> 1;
  const int s16o = w & 1;
  const int row = s16o * 16 + L;
  short8* dst = which ? ksw : qsw;
  const size_t ubase = ((size_t)(b * 256 + sc * 2 + s16o)) * 6;
  float ss = 0.f;
#pragma unroll
  for (int ch = 0; ch < 6; ++ch) {
    short8 fr = *(const short8*)&tile[row * 584 + which * CD + ch * 32 + q * 8];
#pragma unroll
    for (int j = 0; j < 8; ++j) {
      float f = bf2f((unsigned short)fr[j]);
      ss += f * f;
    }
    dst[(ubase + ch) * 64 + lane] = fr;
  }
  ss += __shfl_xor(ss, 16);
  ss += __shfl_xor(ss, 32);                   // sum over 4 quads (192 ch)
  if (lane < 16)
    (which ? k2 : q2)[b * TT + sc * 32 + s16o * 16 + lane] = ss * A2C;

  // v fragments: 12 nt2-units, 3 per wave. lane(q,L): V[q*8+j][nt2*16+L]
  // layout: ((b*128 + sc)*12 + nt2) -> attn2 walks one pointer += 12KB/tile
#pragma unroll
  for (int i = 0; i < 3; ++i) {
    int nt2 = w * 3 + i;
    short8 fr;
#pragma unroll
    for (int j = 0; j < 8; ++j)
      fr[j] = (short)tile[(q * 8 + j) * 584 + 2 * CD + nt2 * 16 + L];
    vsw[((size_t)(b * 128 + sc) * 12 + nt2) * 64 + lane] = fr;
  }
}

// ---------------- main fused attention --------------------------------------
// grid 512 = 8 b x 64 q-tiles; block 256 = 4 waves x 16 q-rows.
// 128 s-iters of 32; K LDS double-buffered via global_load_lds width 16;
// V read straight global->register (L1-resident, no DS cost).
// 33792B LDS -> 2 blocks/CU.
__global__ __launch_bounds__(256, 2) void attn2(
    const short8* __restrict__ qsw, const short8* __restrict__ ksw,
    const short8* __restrict__ vsw, const float* __restrict__ q2,
    const float* __restrict__ k2, float* __restrict__ out) {
  // LDS: K dbuf 2x12KB | P scratch 4 waves x 16x36 fp32
  __shared__ __align__(16) unsigned char s_lds[24576 + 9216];
  float* ldsP = (float*)(s_lds + 24576);

  const int tid = threadIdx.x;
  const int w = tid >> 6;
  const int lane = tid & 63;
  const int L = lane & 15;
  const int q = lane >> 4;
  const int b = blockIdx.x & 7;      // batch -> XCD (and blk, blk+256 same CU
  const int qt = blockIdx.x >> 3;    //   share batch -> shared K/V in L2)
  const int q0 = qt * 64 + w * 16;   // this wave's 16 q-rows
  const size_t bT = (size_t)b * TT;

  float* pw = ldsP + w * 576;        // wave-private 16x36 P scratch

  // K staging pointers (strength-reduced: += const stride per tile)
  const char* gka[3];
  char* lka[3];
#pragma unroll
  for (int j = 0; j < 3; ++j) {
    int u = w * 3 + j;
    gka[j] = (const char*)ksw + ((size_t)(b * 256) * 6 * 64 + u * 64 + lane) * 16;
    lka[j] = (char*)s_lds + u * 1024;
  }
  auto stage = [&](int buf) {
#pragma unroll
    for (int j = 0; j < 3; ++j) {
      __builtin_amdgcn_global_load_lds(
          (const __attribute__((address_space(1))) void*)gka[j],
          (__attribute__((address_space(3))) void*)(lka[j] + buf * 12288), 16, 0, 0);
      gka[j] += 12288;             // 2 s16-units x 6 ch x 64 lanes x 16B
    }
  };

  // V pointer: unit ((b*128 + it)*12 + nt), this lane's 16B
  const char* gv = (const char*)vsw + ((size_t)(b * 128) * 12 * 64 + lane) * 16;

  // Q fragments: unit ((b*256 + s16)*6 + ch), s16 = q0/16 = qt*4 + w
  short8 qf[6];
#pragma unroll
  for (int ch = 0; ch < 6; ++ch)
    qf[ch] = qsw[((size_t)(b * 256 + (q0 >> 4)) * 6 + ch) * 64 + lane];

  float q2l[4];
#pragma unroll
  for (int r = 0; r < 4; ++r) q2l[r] = q2[bT + q0 + 4 * q + r];

  float4v oacc[12];
#pragma unroll
  for (int nt = 0; nt < 12; ++nt) oacc[nt] = (float4v){0.f, 0.f, 0.f, 0.f};
  float lsum[4] = {0.f, 0.f, 0.f, 0.f};

  stage(0);
  // k2 for tile 0 (prefetched each iter thereafter)
  float k2l[2];
  k2l[0] = k2[bT + L];
  k2l[1] = k2[bT + 16 + L];
  __syncthreads();   // drains vmcnt -> K tile0 ready

#pragma unroll 1
  for (int it = 0; it < 128; ++it) {
    const int cur = it & 1;

    // ---- V for THIS tile: global->register, issued first (oldest vmcnt)
    //      so the wait before PV leaves the K staging below in flight ----
    short8 vf[12];
#pragma unroll
    for (int nt = 0; nt < 12; ++nt)
      vf[nt] = *(const short8*)(gv + nt * 1024);
    gv += 12288;

    if (it + 1 < 128) stage(cur ^ 1);   // K prefetch, overlaps compute

    // prefetch next tile's k2 (used next iter; hides scalar-load latency)
    float k2n[2];
    if (it + 1 < 128) {
      k2n[0] = k2[bT + (it + 1) * 32 + L];
      k2n[1] = k2[bT + (it + 1) * 32 + 16 + L];
    }

    // ---- S = Q.K^T from LDS K fragments ----
    float4v sacc[2];
    sacc[0] = (float4v){0.f, 0.f, 0.f, 0.f};
    sacc[1] = (float4v){0.f, 0.f, 0.f, 0.f};
#pragma unroll
    for (int ch = 0; ch < 6; ++ch) {
      short8 kf0 = *(const short8*)(s_lds + cur * 12288 + ch * 1024 + lane * 16);
      short8 kf1 = *(const short8*)(s_lds + cur * 12288 + (6 + ch) * 1024 + lane * 16);
      sacc[0] = __builtin_amdgcn_mfma_f32_16x16x32_bf16(qf[ch], kf0, sacc[0], 0, 0, 0);
      sacc[1] = __builtin_amdgcn_mfma_f32_16x16x32_bf16(qf[ch], kf1, sacc[1], 0, 0, 0);
    }

    // ---- P = exp(-dist); C-layout row=4q+r, col=nt*16+L -> LDS -> A-layout --
#pragma unroll
    for (int nt = 0; nt < 2; ++nt)
#pragma unroll
      for (int r = 0; r < 4; ++r) {
        float dot = sacc[nt][r];
        float tt = fmaf(-2.f * A2C, dot, q2l[r] + k2l[nt]);   // scaled d2
        float y = fmaxf(tt, 0.f);
        float p = __builtin_amdgcn_exp2f(-__builtin_amdgcn_sqrtf(y));
        lsum[r] += p;
        pw[(4 * q + r) * 36 + nt * 16 + L] = p;
      }
    float4v p0 = *(const float4v*)(pw + L * 36 + q * 8);
    float4v p1 = *(const float4v*)(pw + L * 36 + q * 8 + 4);
    // pack 8 fp32 -> 8 bf16 with 4 HW cvt_pk (RNE)
    uint4v pd;
    pd[0] = cvtpk_bf16(p0[0], p0[1]);
    pd[1] = cvtpk_bf16(p0[2], p0[3]);
    pd[2] = cvtpk_bf16(p1[0], p1[1]);
    pd[3] = cvtpk_bf16(p1[2], p1[3]);
    short8 paf = __builtin_bit_cast(short8, pd);

    // ---- O += P.V (V from registers) ----
#pragma unroll
    for (int nt = 0; nt < 12; ++nt)
      oacc[nt] = __builtin_amdgcn_mfma_f32_16x16x32_bf16(paf, vf[nt], oacc[nt], 0, 0, 0);

    k2l[0] = k2n[0];
    k2l[1] = k2n[1];
    __syncthreads();   // drain stage(it+1) + release kbuf[cur]
  }

  // ---- epilogue: normalize, write out (wave-private) ----
#pragma unroll
  for (int r = 0; r < 4; ++r) {
    float ls = lsum[r];
#pragma unroll
    for (int m = 1; m < 16; m <<= 1) ls += __shfl_xor(ls, m);
    float linv = 1.f / ls;
#pragma unroll
    for (int nt = 0; nt < 12; ++nt)
      out[(bT + q0 + 4 * q + r) * CD + nt * 16 + L] = oacc[nt][r] * linv;
  }
}

extern "C" void kernel_launch(void* const* d_in, const int* in_sizes, int n_in,
                              void* d_out, int out_size, void* d_ws, size_t ws_size,
                              hipStream_t stream) {
  (void)in_sizes; (void)n_in; (void)out_size; (void)ws_size;
  const float* qkv = (const float*)d_in[0];
  float* out = (float*)d_out;

  short8* qsw = (short8*)d_ws;                       // 8*256*6 units
  short8* ksw = qsw + (size_t)BB * 256 * 6 * 64;
  short8* vsw = ksw + (size_t)BB * 256 * 6 * 64;     // 8*128*12 units
  float* q2 = (float*)(vsw + (size_t)BB * 12 * 128 * 64);
  float* k2 = q2 + (size_t)BB * TT;

  prep<<<BB * 128, 256, 0, stream>>>(qkv, qsw, ksw, vsw, q2, k2);
  attn2<<<BB * 64, 256, 0, stream>>>(qsw, ksw, vsw, q2, k2, out);
}

// Round 13
// 245.038 us; speedup vs baseline: 1.1911x; 1.1911x over previous
//
#include <hip/hip_runtime.h>
#include <hip/hip_bf16.h>

// QKVAttention: L2-distance attention. B=8, T=4096, C=192, fp32 in/out.
// out[b,t,:] = sum_s exp(-||q_t-k_s||*192^-0.5) v_s / sum_s exp(...)
// exp arg bounded in [-3,0] -> no online softmax needed.
//
// R17: attn2 = R14 VERBATIM (156.5us floor; R15 chain-split and R16
// V-from-global both regressed -> structure closed). Target = the ~88us
// residual (total - attn2), stable across 5 configs; per-launch overhead
// bounded ~5-10us by 3-kernel runs -> prep ~= 75-85us vs ~18us memory floor.
// prep rebuilt:
//  - Q/K fragments: DIRECT global->reg->store (lane(q,L) <- row L, cols
//    ch*32+q*8..+7 = 2x float4), cvt_pk RNE, NO LDS, NO barrier. Sumsq from
//    rounded bf16 (exact diagonal cancellation, bits identical to R15 prep).
//  - V-only LDS tile 32x196 shorts (12.5KB, was 37.4KB): stride 196 ->
//    4-way (not 8-way) conflicts on transpose-emit; 392B row = 8B-aligned.
//  - V loads issued first, consumed after Q/K phase (latency hidden).

#define BB 8
#define TT 4096
#define CD 192

typedef __attribute__((ext_vector_type(8))) short short8;   // 8 bf16 (4 VGPR)
typedef __attribute__((ext_vector_type(4))) float float4v;  // MFMA C/D
typedef __attribute__((ext_vector_type(4))) unsigned uint4v;
typedef __attribute__((ext_vector_type(2))) unsigned int uint2v;

// (log2 e)^2 / 192  : p = exp2(-sqrt(max(q2A+k2A-2*A2C*dot, 0)))
constexpr float A2C = (float)(2.0813689810056077 / 192.0);

static __device__ __forceinline__ float bf2f(unsigned short b) {
  return __builtin_bit_cast(float, (unsigned)b << 16);
}
static __device__ __forceinline__ unsigned cvtpk_bf16(float lo, float hi) {
  unsigned r;                  // D[15:0]=bf16(lo), D[31:16]=bf16(hi), RNE
  asm("v_cvt_pk_bf16_f32 %0, %1, %2" : "=v"(r) : "v"(lo), "v"(hi));
  return r;
}

// ---------------- fused prepass: qkv -> qsw/ksw/vsw fragments + q2/k2 -------
// block = (b, sc): 32 tokens. Q/K: direct per-wave fragment load/convert/
// store (no LDS). V: fp32 -> bf16 LDS tile -> transpose-emit fragments.
__global__ __launch_bounds__(256) void prep(
    const float* __restrict__ qkv, short8* __restrict__ qsw,
    short8* __restrict__ ksw, short8* __restrict__ vsw,
    float* __restrict__ q2, float* __restrict__ k2) {
  __shared__ unsigned short vt[32 * 196];     // 12544 B, 392B row (8B-aligned)
  const int t = threadIdx.x;
  const int b = blockIdx.x >> 7;
  const int sc = blockIdx.x & 127;
  const float* base = qkv + ((size_t)(b * TT + sc * 32)) * (3 * CD);

  // ---- V staging loads: issued FIRST, consumed after the Q/K phase ----
  float4v vx[6];
  int vrow[6], vc4[6];
#pragma unroll
  for (int i = 0; i < 6; ++i) {
    int f = i * 256 + t;                      // 0..1535 = 32 rows x 48 f4
    vrow[i] = f / 48;
    vc4[i] = (f - vrow[i] * 48) * 4;
    vx[i] = *(const float4v*)(base + (size_t)vrow[i] * 576 + 2 * CD + vc4[i]);
  }

  // ---- Q/K direct path (no LDS, no barrier) ----
  const int lane = t & 63, w = t >> 6;
  const int L = lane & 15, q = lane >> 4;
  const int which = w >> 1;                   // waves 0,1 -> Q; 2,3 -> K
  const int s16o = w & 1;
  const float* rp = base + (size_t)(s16o * 16 + L) * 576 + which * CD + q * 8;
  short8* dst = which ? ksw : qsw;
  const size_t ubase = ((size_t)(b * 256 + sc * 2 + s16o)) * 6;
  float ss = 0.f;
#pragma unroll
  for (int ch = 0; ch < 6; ++ch) {
    float4v a = *(const float4v*)(rp + ch * 32);
    float4v c = *(const float4v*)(rp + ch * 32 + 4);
    uint4v pk;
    pk[0] = cvtpk_bf16(a[0], a[1]);
    pk[1] = cvtpk_bf16(a[2], a[3]);
    pk[2] = cvtpk_bf16(c[0], c[1]);
    pk[3] = cvtpk_bf16(c[2], c[3]);
    short8 fr = __builtin_bit_cast(short8, pk);
#pragma unroll
    for (int j = 0; j < 8; ++j) {             // sumsq of ROUNDED values:
      float f = bf2f((unsigned short)fr[j]);  // keeps diagonal d2 == 0
      ss += f * f;
    }
    dst[(ubase + ch) * 64 + lane] = fr;
  }
  ss += __shfl_xor(ss, 16);
  ss += __shfl_xor(ss, 32);                   // sum over 4 quads (192 ch)
  if (lane < 16)
    (which ? k2 : q2)[b * TT + sc * 32 + s16o * 16 + lane] = ss * A2C;

  // ---- V: cvt + LDS tile, barrier, transpose-emit fragments ----
#pragma unroll
  for (int i = 0; i < 6; ++i) {
    uint2v r;
    r[0] = cvtpk_bf16(vx[i][0], vx[i][1]);
    r[1] = cvtpk_bf16(vx[i][2], vx[i][3]);
    *(uint2v*)&vt[vrow[i] * 196 + vc4[i]] = r;
  }
  __syncthreads();
  // 12 nt2-units, 3 per wave. lane(q,L): V[q*8+j][nt2*16+L]
#pragma unroll
  for (int i = 0; i < 3; ++i) {
    int nt2 = w * 3 + i;
    short8 fr;
#pragma unroll
    for (int j = 0; j < 8; ++j)
      fr[j] = (short)vt[(q * 8 + j) * 196 + nt2 * 16 + L];
    vsw[((size_t)(b * 12 + nt2) * 128 + sc) * 64 + lane] = fr;
  }
}

// ---------------- main fused attention (R14 verbatim, 156.5us) --------------
// grid 512 = 8 b x 64 q-tiles; block 256 = 4 waves x 16 q-rows.
// 128 s-iters of 32; K,V LDS double-buffered via global_load_lds width 16.
// 58368B LDS -> 2 blocks/CU (independent barriers overlap each other's drain).
__global__ __launch_bounds__(256, 2) void attn2(
    const short8* __restrict__ qsw, const short8* __restrict__ ksw,
    const short8* __restrict__ vsw, const float* __restrict__ q2,
    const float* __restrict__ k2, float* __restrict__ out) {
  // LDS: K dbuf 2x12KB | V dbuf 2x12KB | P scratch 4 waves x 16x36 fp32
  __shared__ __align__(16) unsigned char s_lds[49152 + 9216];
  float* ldsP = (float*)(s_lds + 49152);

  const int tid = threadIdx.x;
  const int w = tid >> 6;
  const int lane = tid & 63;
  const int L = lane & 15;
  const int q = lane >> 4;
  const int b = blockIdx.x & 7;      // batch -> XCD (and blk, blk+256 same CU
  const int qt = blockIdx.x >> 3;    //   share batch -> shared K/V in L2)
  const int q0 = qt * 64 + w * 16;   // this wave's 16 q-rows
  const size_t bT = (size_t)b * TT;

  float* pw = ldsP + w * 576;        // wave-private 16x36 P scratch

  // staging pointers (strength-reduced: += const stride per tile)
  const char* gka[3];
  const char* gva[3];
  char* lka[3];
  char* lva[3];
#pragma unroll
  for (int j = 0; j < 3; ++j) {
    int u = w * 3 + j;
    gka[j] = (const char*)ksw + ((size_t)(b * 256) * 6 * 64 + u * 64 + lane) * 16;
    gva[j] = (const char*)vsw + (((size_t)(b * 12 + u) * 128) * 64 + lane) * 16;
    lka[j] = (char*)s_lds + u * 1024;
    lva[j] = (char*)s_lds + 24576 + u * 1024;
  }
  // issue stage of current tile into buf, advance pointers to next tile
  auto stage = [&](int buf) {
#pragma unroll
    for (int j = 0; j < 3; ++j) {
      __builtin_amdgcn_global_load_lds(
          (const __attribute__((address_space(1))) void*)gka[j],
          (__attribute__((address_space(3))) void*)(lka[j] + buf * 12288), 16, 0, 0);
      gka[j] += 12288;             // 2 s16-units x 6 ch x 64 lanes x 16B
    }
#pragma unroll
    for (int j = 0; j < 3; ++j) {
      __builtin_amdgcn_global_load_lds(
          (const __attribute__((address_space(1))) void*)gva[j],
          (__attribute__((address_space(3))) void*)(lva[j] + buf * 12288), 16, 0, 0);
      gva[j] += 1024;              // 64 lanes x 16B per itile
    }
  };

  // Q fragments: unit ((b*256 + s16)*6 + ch), s16 = q0/16 = qt*4 + w
  short8 qf[6];
#pragma unroll
  for (int ch = 0; ch < 6; ++ch)
    qf[ch] = qsw[((size_t)(b * 256 + (q0 >> 4)) * 6 + ch) * 64 + lane];

  float q2l[4];
#pragma unroll
  for (int r = 0; r < 4; ++r) q2l[r] = q2[bT + q0 + 4 * q + r];

  float4v oacc[12];
#pragma unroll
  for (int nt = 0; nt < 12; ++nt) oacc[nt] = (float4v){0.f, 0.f, 0.f, 0.f};
  float lsum[4] = {0.f, 0.f, 0.f, 0.f};

  stage(0);
  // k2 for tile 0 (prefetched each iter thereafter)
  float k2l[2];
  k2l[0] = k2[bT + L];
  k2l[1] = k2[bT + 16 + L];
  __syncthreads();   // drains vmcnt -> tile0 ready

#pragma unroll 1
  for (int it = 0; it < 128; ++it) {
    const int cur = it & 1;
    if (it + 1 < 128) stage(cur ^ 1);   // overlap with compute

    // prefetch next tile's k2 (used next iter; hides scalar-load latency)
    float k2n[2];
    if (it + 1 < 128) {
      k2n[0] = k2[bT + (it + 1) * 32 + L];
      k2n[1] = k2[bT + (it + 1) * 32 + 16 + L];
    }

    // ---- S = Q.K^T from LDS K fragments ----
    float4v sacc[2];
    sacc[0] = (float4v){0.f, 0.f, 0.f, 0.f};
    sacc[1] = (float4v){0.f, 0.f, 0.f, 0.f};
#pragma unroll
    for (int ch = 0; ch < 6; ++ch) {
      short8 kf0 = *(const short8*)(s_lds + cur * 12288 + ch * 1024 + lane * 16);
      short8 kf1 = *(const short8*)(s_lds + cur * 12288 + (6 + ch) * 1024 + lane * 16);
      sacc[0] = __builtin_amdgcn_mfma_f32_16x16x32_bf16(qf[ch], kf0, sacc[0], 0, 0, 0);
      sacc[1] = __builtin_amdgcn_mfma_f32_16x16x32_bf16(qf[ch], kf1, sacc[1], 0, 0, 0);
    }

    // ---- V fragments from LDS (issue early; used after P) ----
    short8 vf[12];
#pragma unroll
    for (int nt = 0; nt < 12; ++nt)
      vf[nt] = *(const short8*)(s_lds + 24576 + cur * 12288 + nt * 1024 + lane * 16);

    // ---- P = exp(-dist); C-layout row=4q+r, col=nt*16+L -> LDS -> A-layout --
#pragma unroll
    for (int nt = 0; nt < 2; ++nt)
#pragma unroll
      for (int r = 0; r < 4; ++r) {
        float dot = sacc[nt][r];
        float tt = fmaf(-2.f * A2C, dot, q2l[r] + k2l[nt]);   // scaled d2
        float y = fmaxf(tt, 0.f);
        float p = __builtin_amdgcn_exp2f(-__builtin_amdgcn_sqrtf(y));
        lsum[r] += p;
        pw[(4 * q + r) * 36 + nt * 16 + L] = p;
      }
    float4v p0 = *(const float4v*)(pw + L * 36 + q * 8);
    float4v p1 = *(const float4v*)(pw + L * 36 + q * 8 + 4);
    // pack 8 fp32 -> 8 bf16 with 4 HW cvt_pk (RNE)
    uint4v pd;
    pd[0] = cvtpk_bf16(p0[0], p0[1]);
    pd[1] = cvtpk_bf16(p0[2], p0[3]);
    pd[2] = cvtpk_bf16(p1[0], p1[1]);
    pd[3] = cvtpk_bf16(p1[2], p1[3]);
    short8 paf = __builtin_bit_cast(short8, pd);

    // ---- O += P.V ----
#pragma unroll
    for (int nt = 0; nt < 12; ++nt)
      oacc[nt] = __builtin_amdgcn_mfma_f32_16x16x32_bf16(paf, vf[nt], oacc[nt], 0, 0, 0);

    k2l[0] = k2n[0];
    k2l[1] = k2n[1];
    __syncthreads();   // drain stage(it+1) + release buf[cur]
  }

  // ---- epilogue: normalize, write out (wave-private) ----
#pragma unroll
  for (int r = 0; r < 4; ++r) {
    float ls = lsum[r];
#pragma unroll
    for (int m = 1; m < 16; m <<= 1) ls += __shfl_xor(ls, m);
    float linv = 1.f / ls;
#pragma unroll
    for (int nt = 0; nt < 12; ++nt)
      out[(bT + q0 + 4 * q + r) * CD + nt * 16 + L] = oacc[nt][r] * linv;
  }
}

extern "C" void kernel_launch(void* const* d_in, const int* in_sizes, int n_in,
                              void* d_out, int out_size, void* d_ws, size_t ws_size,
                              hipStream_t stream) {
  (void)in_sizes; (void)n_in; (void)out_size; (void)ws_size;
  const float* qkv = (const float*)d_in[0];
  float* out = (float*)d_out;

  short8* qsw = (short8*)d_ws;                       // 8*256*6 units
  short8* ksw = qsw + (size_t)BB * 256 * 6 * 64;
  short8* vsw = ksw + (size_t)BB * 256 * 6 * 64;     // 8*12*128 units
  float* q2 = (float*)(vsw + (size_t)BB * 12 * 128 * 64);
  float* k2 = q2 + (size_t)BB * TT;

  prep<<<BB * 128, 256, 0, stream>>>(qkv, qsw, ksw, vsw, q2, k2);
  attn2<<<BB * 64, 256, 0, stream>>>(qsw, ksw, vsw, q2, k2, out);
}